// Round 6
// baseline (191.900 us; speedup 1.0000x reference)
//
#include <hip/hip_runtime.h>
#include <math.h>

// log(2*pi) + 1
#define LOG_2PI_PLUS_1 2.8378770664093454835606594728112

#define NBLOCKS 2048

// ws layout: ws[0..NBLOCKS) floats = per-block partial sums. Every slot is
// unconditionally written by the main kernel, so harness 0xAA poison needs no
// memset node.
//
// LESSONS:
//  R2/R3: device-scope __threadfence() in the hot kernel → per-XCD L2
//         writeback/invalidate storm, +75 us. Never fence the hot loop.
//  R5:    2048 same-address device atomicAdds serialize (~10 us) — plain
//         per-block stores + separate finalize kernel instead; the
//         kernel->kernel graph-node boundary is a free device-wide sync.
//  R6:    OccupancyPercent ~49% => ~16 waves/CU resident; 1 outstanding
//         1-KiB load/wave is marginal vs BW*latency (~9-12 KiB/CU needed).
//         4-deep unroll w/ independent loads quadruples in-flight bytes.
//
// Precision: total ~= 3.1e7, out = log1p(total) => d(out)/d(sum) ~= 3.2e-8.
// Output threshold 0.345 allows ~1e7 absolute sum error; fp32 accumulation
// error here is ~1e3-1e4. Safe by 3+ orders of magnitude.
__global__ __launch_bounds__(256) void masked_logsum_kernel(
    const float* __restrict__ x, long long n, float* __restrict__ partials) {
  const long long n4 = n >> 2;
  const float4* __restrict__ x4 = (const float4*)x;
  const long long tid = (long long)blockIdx.x * blockDim.x + threadIdx.x;
  const long long stride = (long long)gridDim.x * blockDim.x;

  // Grid-stride, 4 independent float4 loads in flight per iteration.
  // For n = 4096*8192: exactly 4 outer iterations per thread, no tail.
  float acc0 = 0.0f, acc1 = 0.0f, acc2 = 0.0f, acc3 = 0.0f;
  long long i = tid;
  for (; i + 3 * stride < n4; i += 4 * stride) {
    float4 a = x4[i];
    float4 b = x4[i + stride];
    float4 c = x4[i + 2 * stride];
    float4 d = x4[i + 3 * stride];
    float sa = 0.0f, sb = 0.0f, sc = 0.0f, sd = 0.0f;
    sa += (a.x != 0.0f) ? __logf(a.x) : 0.0f;
    sa += (a.y != 0.0f) ? __logf(a.y) : 0.0f;
    sa += (a.z != 0.0f) ? __logf(a.z) : 0.0f;
    sa += (a.w != 0.0f) ? __logf(a.w) : 0.0f;
    sb += (b.x != 0.0f) ? __logf(b.x) : 0.0f;
    sb += (b.y != 0.0f) ? __logf(b.y) : 0.0f;
    sb += (b.z != 0.0f) ? __logf(b.z) : 0.0f;
    sb += (b.w != 0.0f) ? __logf(b.w) : 0.0f;
    sc += (c.x != 0.0f) ? __logf(c.x) : 0.0f;
    sc += (c.y != 0.0f) ? __logf(c.y) : 0.0f;
    sc += (c.z != 0.0f) ? __logf(c.z) : 0.0f;
    sc += (c.w != 0.0f) ? __logf(c.w) : 0.0f;
    sd += (d.x != 0.0f) ? __logf(d.x) : 0.0f;
    sd += (d.y != 0.0f) ? __logf(d.y) : 0.0f;
    sd += (d.z != 0.0f) ? __logf(d.z) : 0.0f;
    sd += (d.w != 0.0f) ? __logf(d.w) : 0.0f;
    acc0 += sa;
    acc1 += sb;
    acc2 += sc;
    acc3 += sd;
  }
  for (; i < n4; i += stride) {
    float4 a = x4[i];
    float sa = 0.0f;
    sa += (a.x != 0.0f) ? __logf(a.x) : 0.0f;
    sa += (a.y != 0.0f) ? __logf(a.y) : 0.0f;
    sa += (a.z != 0.0f) ? __logf(a.z) : 0.0f;
    sa += (a.w != 0.0f) ? __logf(a.w) : 0.0f;
    acc0 += sa;
  }
  float acc = (acc0 + acc1) + (acc2 + acc3);

  // scalar tail (n % 4) — n = 4096*8192 so never runs; kept for generality.
  if (tid == 0) {
    for (long long j = n4 << 2; j < n; ++j) {
      float v = x[j];
      acc += (v != 0.0f) ? __logf(v) : 0.0f;
    }
  }

  // 64-lane wave butterfly (wave64!)
  #pragma unroll
  for (int off = 32; off > 0; off >>= 1) {
    acc += __shfl_down(acc, off, 64);
  }

  __shared__ float smem[4];  // 256 threads / 64 lanes = 4 waves
  const int lane = threadIdx.x & 63;
  const int wave = threadIdx.x >> 6;
  if (lane == 0) smem[wave] = acc;
  __syncthreads();

  if (threadIdx.x == 0) {
    // Plain store, one per block. NO atomic, NO fence.
    partials[blockIdx.x] = (smem[0] + smem[1]) + (smem[2] + smem[3]);
  }
}

// One block reduces the NBLOCKS partials and writes the scalar output.
__global__ __launch_bounds__(256) void finalize_kernel(
    const float* __restrict__ partials, float* __restrict__ out,
    double mn_half) {
  float acc = 0.0f;
  for (int i = threadIdx.x; i < NBLOCKS; i += 256) acc += partials[i];

  #pragma unroll
  for (int off = 32; off > 0; off >>= 1) {
    acc += __shfl_down(acc, off, 64);
  }

  __shared__ float smem[4];
  const int lane = threadIdx.x & 63;
  const int wave = threadIdx.x >> 6;
  if (lane == 0) smem[wave] = acc;
  __syncthreads();

  if (threadIdx.x == 0) {
    float sumD = (smem[0] + smem[1]) + (smem[2] + smem[3]);
    double total = mn_half * LOG_2PI_PLUS_1 + 0.5 * (double)sumD;
    out[0] = (total > 0.0) ? (float)log1p(total) : 1.0f;
  }
}

extern "C" void kernel_launch(void* const* d_in, const int* in_sizes, int n_in,
                              void* d_out, int out_size, void* d_ws, size_t ws_size,
                              hipStream_t stream) {
  const float* x = (const float*)d_in[0];
  long long n = (long long)in_sizes[0];
  float* partials = (float*)d_ws;

  // No memset: every partials[0..NBLOCKS) slot is written by the main kernel.
  masked_logsum_kernel<<<NBLOCKS, 256, 0, stream>>>(x, n, partials);
  finalize_kernel<<<1, 256, 0, stream>>>(partials, (float*)d_out,
                                         0.5 * (double)n);
}

// Round 7
// 180.410 us; speedup vs baseline: 1.0637x; 1.0637x over previous
//
#include <hip/hip_runtime.h>
#include <math.h>

// log(2*pi) + 1
#define LOG_2PI_PLUS_1 2.8378770664093454835606594728112

#define NBLOCKS 2048

typedef float f32x4 __attribute__((ext_vector_type(4)));

// ws layout: ws[0..NBLOCKS) floats = per-block partial sums. Every slot is
// unconditionally written by the main kernel, so harness 0xAA poison needs no
// memset node.
//
// LESSONS:
//  R2/R3: device-scope __threadfence() in hot kernel → per-XCD L2 writeback
//         storm, +75 us. Never fence the hot loop.
//  R5:    2048 same-address device atomicAdds serialize — use plain
//         per-block stores + separate finalize kernel (graph-node boundary
//         is a free device-wide sync). WIN: 202→186.
//  R6:    4-deep unroll (4x in-flight loads/wave) NEUTRAL-to-worse: per-wave
//         MLP was never the limiter at 32 waves/CU. Keep the simple loop.
//  R7:    read-once 134 MB stream through 32 MB aggregate L2 → try
//         nontemporal (evict-first) loads.
//
// Precision: total ~= 3.1e7, out = log1p(total) => d(out)/d(sum) ~= 3.2e-8.
// Output threshold 0.345 allows ~1e7 absolute sum error; fp32 accumulation
// error is ~1e3-1e4. Safe by 3+ orders of magnitude.
__global__ __launch_bounds__(256) void masked_logsum_kernel(
    const float* __restrict__ x, long long n, float* __restrict__ partials) {
  const long long n4 = n >> 2;
  const f32x4* __restrict__ x4 = (const f32x4*)x;
  const long long tid = (long long)blockIdx.x * blockDim.x + threadIdx.x;
  const long long stride = (long long)gridDim.x * blockDim.x;

  // R5's empirically-fast loop, with nontemporal (evict-first) 16B loads.
  float acc = 0.0f;
  for (long long i = tid; i < n4; i += stride) {
    f32x4 v = __builtin_nontemporal_load(&x4[i]);
    float s = 0.0f;
    s += (v.x != 0.0f) ? __logf(v.x) : 0.0f;
    s += (v.y != 0.0f) ? __logf(v.y) : 0.0f;
    s += (v.z != 0.0f) ? __logf(v.z) : 0.0f;
    s += (v.w != 0.0f) ? __logf(v.w) : 0.0f;
    acc += s;
  }

  // scalar tail (n % 4) — n = 4096*8192 so never runs; kept for generality.
  if (tid == 0) {
    for (long long j = n4 << 2; j < n; ++j) {
      float v = x[j];
      acc += (v != 0.0f) ? __logf(v) : 0.0f;
    }
  }

  // 64-lane wave butterfly (wave64!)
  #pragma unroll
  for (int off = 32; off > 0; off >>= 1) {
    acc += __shfl_down(acc, off, 64);
  }

  __shared__ float smem[4];  // 256 threads / 64 lanes = 4 waves
  const int lane = threadIdx.x & 63;
  const int wave = threadIdx.x >> 6;
  if (lane == 0) smem[wave] = acc;
  __syncthreads();

  if (threadIdx.x == 0) {
    // Plain store, one per block. NO atomic, NO fence.
    partials[blockIdx.x] = (smem[0] + smem[1]) + (smem[2] + smem[3]);
  }
}

// One block reduces the NBLOCKS partials and writes the scalar output.
__global__ __launch_bounds__(256) void finalize_kernel(
    const float* __restrict__ partials, float* __restrict__ out,
    double mn_half) {
  float acc = 0.0f;
  for (int i = threadIdx.x; i < NBLOCKS; i += 256) acc += partials[i];

  #pragma unroll
  for (int off = 32; off > 0; off >>= 1) {
    acc += __shfl_down(acc, off, 64);
  }

  __shared__ float smem[4];
  const int lane = threadIdx.x & 63;
  const int wave = threadIdx.x >> 6;
  if (lane == 0) smem[wave] = acc;
  __syncthreads();

  if (threadIdx.x == 0) {
    float sumD = (smem[0] + smem[1]) + (smem[2] + smem[3]);
    double total = mn_half * LOG_2PI_PLUS_1 + 0.5 * (double)sumD;
    out[0] = (total > 0.0) ? (float)log1p(total) : 1.0f;
  }
}

extern "C" void kernel_launch(void* const* d_in, const int* in_sizes, int n_in,
                              void* d_out, int out_size, void* d_ws, size_t ws_size,
                              hipStream_t stream) {
  const float* x = (const float*)d_in[0];
  long long n = (long long)in_sizes[0];
  float* partials = (float*)d_ws;

  // No memset: every partials[0..NBLOCKS) slot is written by the main kernel.
  masked_logsum_kernel<<<NBLOCKS, 256, 0, stream>>>(x, n, partials);
  finalize_kernel<<<1, 256, 0, stream>>>(partials, (float*)d_out,
                                         0.5 * (double)n);
}

// Round 8
// 178.657 us; speedup vs baseline: 1.0741x; 1.0098x over previous
//
#include <hip/hip_runtime.h>
#include <math.h>

// log(2*pi) + 1
#define LOG_2PI_PLUS_1 2.8378770664093454835606594728112

#define NBLOCKS 1024
#define BLOCK 512  // 8 waves/block; 1024 blocks = 4 blocks/CU = 32 waves/CU

typedef float f32x4 __attribute__((ext_vector_type(4)));

// ws layout: ws[0..NBLOCKS) floats = per-block partial sums. Every slot is
// unconditionally written by the main kernel, so harness 0xAA poison needs no
// memset node.
//
// LESSONS (journal):
//  R2/R3: device-scope __threadfence() in hot kernel → per-XCD L2
//         writeback/invalidate storm, +75 us. Never fence the hot loop.
//  R5:    2048 same-address device atomicAdds serialize — plain per-block
//         stores + separate finalize kernel (graph-node boundary is a free
//         device-wide sync). WIN 202→186.
//  R6:    4-deep stride-unroll NEUTRAL-WORSE: per-wave MLP not the limiter
//         at 32 waves/CU; it also quadruples the instantaneous sweep window
//         (8→32 MiB), hurting DRAM/L3 locality. Keep the simple loop.
//  R7:    nontemporal (evict-first) loads on the read-once 134 MB stream:
//         WIN 186→180.
//  R8:    geometry probe 2048x256 → 1024x512 (same occupancy & window,
//         half the block epilogues).
//
// Precision: total ~= 3.1e7, out = log1p(total) => d(out)/d(sum) ~= 3.2e-8.
// Output threshold 0.345 allows ~1e7 absolute sum error; fp32 accumulation
// error is ~1e3-1e4. Safe by 3+ orders of magnitude.
__global__ __launch_bounds__(BLOCK) void masked_logsum_kernel(
    const float* __restrict__ x, long long n, float* __restrict__ partials) {
  const long long n4 = n >> 2;
  const f32x4* __restrict__ x4 = (const f32x4*)x;
  const long long tid = (long long)blockIdx.x * blockDim.x + threadIdx.x;
  const long long stride = (long long)gridDim.x * blockDim.x;

  // Simple grid-stride: the whole GPU sweeps one contiguous 8 MiB window per
  // iteration (total-stride = 524288 float4). nt = evict-first.
  float acc = 0.0f;
  for (long long i = tid; i < n4; i += stride) {
    f32x4 v = __builtin_nontemporal_load(&x4[i]);
    float s = 0.0f;
    s += (v.x != 0.0f) ? __logf(v.x) : 0.0f;
    s += (v.y != 0.0f) ? __logf(v.y) : 0.0f;
    s += (v.z != 0.0f) ? __logf(v.z) : 0.0f;
    s += (v.w != 0.0f) ? __logf(v.w) : 0.0f;
    acc += s;
  }

  // scalar tail (n % 4) — n = 4096*8192 so never runs; kept for generality.
  if (tid == 0) {
    for (long long j = n4 << 2; j < n; ++j) {
      float v = x[j];
      acc += (v != 0.0f) ? __logf(v) : 0.0f;
    }
  }

  // 64-lane wave butterfly (wave64!)
  #pragma unroll
  for (int off = 32; off > 0; off >>= 1) {
    acc += __shfl_down(acc, off, 64);
  }

  __shared__ float smem[BLOCK / 64];  // 8 waves
  const int lane = threadIdx.x & 63;
  const int wave = threadIdx.x >> 6;
  if (lane == 0) smem[wave] = acc;
  __syncthreads();

  if (threadIdx.x == 0) {
    float t = 0.0f;
    #pragma unroll
    for (int w = 0; w < BLOCK / 64; ++w) t += smem[w];
    // Plain store, one per block. NO atomic, NO fence.
    partials[blockIdx.x] = t;
  }
}

// One block reduces the NBLOCKS partials and writes the scalar output.
__global__ __launch_bounds__(256) void finalize_kernel(
    const float* __restrict__ partials, float* __restrict__ out,
    double mn_half) {
  float acc = 0.0f;
  for (int i = threadIdx.x; i < NBLOCKS; i += 256) acc += partials[i];

  #pragma unroll
  for (int off = 32; off > 0; off >>= 1) {
    acc += __shfl_down(acc, off, 64);
  }

  __shared__ float smem[4];
  const int lane = threadIdx.x & 63;
  const int wave = threadIdx.x >> 6;
  if (lane == 0) smem[wave] = acc;
  __syncthreads();

  if (threadIdx.x == 0) {
    float sumD = (smem[0] + smem[1]) + (smem[2] + smem[3]);
    double total = mn_half * LOG_2PI_PLUS_1 + 0.5 * (double)sumD;
    out[0] = (total > 0.0) ? (float)log1p(total) : 1.0f;
  }
}

extern "C" void kernel_launch(void* const* d_in, const int* in_sizes, int n_in,
                              void* d_out, int out_size, void* d_ws, size_t ws_size,
                              hipStream_t stream) {
  const float* x = (const float*)d_in[0];
  long long n = (long long)in_sizes[0];
  float* partials = (float*)d_ws;

  // No memset: every partials[0..NBLOCKS) slot is written by the main kernel.
  masked_logsum_kernel<<<NBLOCKS, BLOCK, 0, stream>>>(x, n, partials);
  finalize_kernel<<<1, 256, 0, stream>>>(partials, (float*)d_out,
                                         0.5 * (double)n);
}